// Round 12
// baseline (188.082 us; speedup 1.0000x reference)
//
#include <hip/hip_runtime.h>

typedef __attribute__((ext_vector_type(4))) float f32x4;
typedef __attribute__((ext_vector_type(8))) short bf16x8;

__device__ __forceinline__ unsigned short f2b(float f) {
  unsigned u = __float_as_uint(f);
  u = (u + 0x7FFFu + ((u >> 16) & 1u)) >> 16;
  return (unsigned short)u;
}

#define BAR() asm volatile("s_barrier" ::: "memory")
#define VMCNT(N) asm volatile("s_waitcnt vmcnt(" #N ")" ::: "memory")
#define LGKM0() asm volatile("s_waitcnt lgkmcnt(0)" ::: "memory")
#define SBAR0() __builtin_amdgcn_sched_barrier(0)

// ---------------- K1: {selector + skill-mix} ∪ {W f32->bf16} ----------------
__global__ void combine_wconv_kernel(const float* __restrict__ logits,   // [32][8]
                                     const int*   __restrict__ tasks,    // [8]
                                     const float* __restrict__ A,        // [8][2048][16]
                                     const float* __restrict__ B,        // [8][16][2048]
                                     const float* __restrict__ W,        // [2048][2048]
                                     unsigned short* __restrict__ Art,   // [8][16][2048]
                                     unsigned short* __restrict__ Brt,   // [8][2048][16]
                                     unsigned short* __restrict__ Wb)    // [2048][2048]
{
  int blk = blockIdx.x;
  int tid = threadIdx.x;
  if (blk >= 64) {
    int idx0 = (blk - 64) * 256 + tid;
    #pragma unroll
    for (int c = 0; c < 32; ++c) {
      size_t i = ((size_t)idx0 + (size_t)c * 32768) * 4;
      f32x4 v = *(const f32x4*)(W + i);
      ushort4 o;
      o.x = f2b(v.x); o.y = f2b(v.y); o.z = f2b(v.z); o.w = f2b(v.w);
      *(ushort4*)(Wb + i) = o;
    }
    return;
  }
  int idx = blk * 256 + tid;
  int b = idx >> 11;
  int i = idx & 2047;
  int task = tasks[b];
  float p[8]; float s = 0.f;
  #pragma unroll
  for (int t = 0; t < 8; ++t) {
    float l = logits[task * 8 + t];
    float e = 1.f / (1.f + __expf(-l));
    p[t] = e; s += e;
  }
  float inv = 1.f / (s + 1e-12f);
  #pragma unroll
  for (int t = 0; t < 8; ++t) p[t] *= inv;

  float ar[16];
  #pragma unroll
  for (int r = 0; r < 16; ++r) ar[r] = 0.f;
  for (int t = 0; t < 8; ++t) {
    const float* ap = A + ((size_t)t * 2048 + i) * 16;
    float pt = p[t];
    #pragma unroll
    for (int r = 0; r < 16; ++r) ar[r] += pt * ap[r];
  }
  #pragma unroll
  for (int r = 0; r < 16; ++r)
    Art[((size_t)b * 16 + r) * 2048 + i] = f2b(ar[r]);

  float br[16];
  #pragma unroll
  for (int r = 0; r < 16; ++r) br[r] = 0.f;
  for (int t = 0; t < 8; ++t) {
    float pt = p[t];
    #pragma unroll
    for (int r = 0; r < 16; ++r) br[r] += pt * B[((size_t)t * 16 + r) * 2048 + i];
  }
  #pragma unroll
  for (int r = 0; r < 16; ++r)
    Brt[((size_t)b * 2048 + i) * 16 + r] = f2b(br[r] * 0.0625f);
}

// ---------------- K2: xa = x @ A_mix (prep minus xb write; also warms x in L3) ----------------
__global__ void xa_kernel(const float* __restrict__ x,            // [16384][2048]
                          const unsigned short* __restrict__ Art, // [8][16][2048]
                          unsigned short* __restrict__ xa)        // [16384][16]
{
  __shared__ float red[4][16][16];
  int blk = blockIdx.x;
  int tid = threadIdx.x;
  int lane = tid & 63, wv = tid >> 6;
  int lr = lane & 15, hi = lane >> 4;
  int rowbase = blk * 16;
  int batch = rowbase >> 11;
  int row = rowbase + lr;
  f32x4 acc; acc.x = 0.f; acc.y = 0.f; acc.z = 0.f; acc.w = 0.f;
  const float* xrow = x + (size_t)row * 2048 + wv * 512 + hi * 8;
  const unsigned short* artrow = Art + ((size_t)batch * 16 + lr) * 2048 + wv * 512 + hi * 8;
  #pragma unroll
  for (int ks = 0; ks < 16; ++ks) {
    f32x4 v0 = *(const f32x4*)(xrow + ks * 32);
    f32x4 v1 = *(const f32x4*)(xrow + ks * 32 + 4);
    bf16x8 av;
    av[0] = (short)f2b(v0.x); av[1] = (short)f2b(v0.y);
    av[2] = (short)f2b(v0.z); av[3] = (short)f2b(v0.w);
    av[4] = (short)f2b(v1.x); av[5] = (short)f2b(v1.y);
    av[6] = (short)f2b(v1.z); av[7] = (short)f2b(v1.w);
    bf16x8 bv = *(const bf16x8*)(artrow + ks * 32);
    acc = __builtin_amdgcn_mfma_f32_16x16x32_bf16(av, bv, acc, 0, 0, 0);
  }
  #pragma unroll
  for (int j = 0; j < 4; ++j) red[wv][hi * 4 + j][lr] = acc[j];
  __syncthreads();
  int rr = tid >> 4, cc = tid & 15;
  float s = red[0][rr][cc] + red[1][rr][cc] + red[2][rr][cc] + red[3][rr][cc];
  xa[(size_t)(rowbase + rr) * 16 + cc] = f2b(s);
}

// ---------------- K3: 256x256 GEMM, fused x f32->bf16 staging (xb eliminated) ----------------
// 512 thr = 8 waves (2 x 4); per-wave out 128x64; LDS 128KB 2-buf (A 32K linear [256][128B]
// swizzled, B 32K = R7 region layout). 1 barrier per K-tile:
//   stage kt+1 (B via gload_lds, A via f32 reg-load split g01/g23 + cvt + lane-linear ds_write)
//   overlapped with frag reads + 4 MFMA quadrants of kt; LGKM0+VMCNT(0)+BAR publishes.
// WAR: nbuf written during kt was last read in kt-1, before BAR(kt-1) -> safe.
// RAW: VMCNT(0) lands B gloads (1-tile flight); ds_write A drained by LGKM0 -> BAR publishes.
// Both-sides swizzle (rule 21): A source k pre-swizzled per (row,chunk); reads apply same XOR.
__global__ __launch_bounds__(512, 2)
void gemm_kernel(const float* __restrict__ x,            // [16384][2048] f32
                 const unsigned short* __restrict__ Wb,  // [2048][2048]  bf16 (row = out col)
                 const float* __restrict__ bias,         // [2048]
                 const unsigned short* __restrict__ xa,  // [16384][16]   bf16
                 const unsigned short* __restrict__ Brt, // [8][2048][16] bf16 (pre-scaled 1/16)
                 float* __restrict__ out)                // [16384][2048] f32
{
  __shared__ __align__(16) char lds[131072];
  const int tid = threadIdx.x;
  const int lane = tid & 63;
  const int wv = tid >> 6;
  const int wr = wv >> 2, wc = wv & 3;
  const int lr = lane & 15, hi = lane >> 4;
  const int hi16 = hi * 16;

  // XCD-contiguous tm-octet swizzle: XCD x owns tm in [x*8, x*8+8); tn walks fast.
  const int bid = blockIdx.x;
  const int xcd = bid & 7, q = bid >> 3;        // q in [0,64)
  const int tm = xcd * 8 + (q >> 3);
  const int tn = q & 7;
  const int rowbase = tm * 256, colbase = tn * 256;

  // B staging geometry (R7, validated): thread stages row0, chunk tid&7, inv-swizzled src col
  const int row0 = tid >> 3;
  const int cb0 = (tid & 7) * 16;
  const int scb_e = (cb0 ^ ((row0 & 7) << 4)) >> 1;
  const int rb5 = ((row0 >> 5) << 6) + (row0 & 31);

  // A staging geometry: wave wv writes A-phys [wv*4KB, +4KB) as 4 lane-linear ds_write groups.
  // phys off = wv*4096 + g*1024 + lane*16 -> (arow = off>>7, pcb = off&127);
  // source k bytes = pcb ^ ((arow&7)<<4)  (involution; read side applies same XOR).
  int aoffk[4];
  #pragma unroll
  for (int g = 0; g < 4; ++g) {
    int off = wv * 4096 + g * 1024 + lane * 16;
    int arow = off >> 7;
    int scb = (off & 127) ^ ((arow & 7) << 4);
    aoffk[g] = arow * 2048 + (scb >> 1);
  }
  const float* xbase = x + (size_t)rowbase * 2048;
  const int aphys0 = wv * 4096 + lane * 16;

#define GL16(LDSOFF, GPTR) \
  __builtin_amdgcn_global_load_lds((const __attribute__((address_space(1))) unsigned int*)(GPTR), \
      (__attribute__((address_space(3))) unsigned int*)(lds + (LDSOFF)), 16, 0, 0)

#define STAGE_B(NH, DBUF, KOFF) { \
  const unsigned short* g_ = Wb + (size_t)(colbase + (NH)*32 + rb5) * 2048 + (KOFF) + scb_e; \
  GL16((DBUF)*65536 + 32768 + (NH)*16384 + tid*16, g_); \
  GL16((DBUF)*65536 + 32768 + (NH)*16384 + 8192 + tid*16, g_ + 128*2048); \
}

#define LOAD_A2(G0, KO) { \
  _Pragma("unroll") \
  for (int g = (G0); g < (G0) + 2; ++g) { \
    const float* p_ = xbase + aoffk[g] + (KO); \
    va[2*g]   = *(const f32x4*)(p_); \
    va[2*g+1] = *(const f32x4*)(p_ + 4); \
  } \
}
#define WRITE_A2(G0, NBUF) { \
  _Pragma("unroll") \
  for (int g = (G0); g < (G0) + 2; ++g) { \
    bf16x8 w_; \
    w_[0]=(short)f2b(va[2*g].x);   w_[1]=(short)f2b(va[2*g].y); \
    w_[2]=(short)f2b(va[2*g].z);   w_[3]=(short)f2b(va[2*g].w); \
    w_[4]=(short)f2b(va[2*g+1].x); w_[5]=(short)f2b(va[2*g+1].y); \
    w_[6]=(short)f2b(va[2*g+1].z); w_[7]=(short)f2b(va[2*g+1].w); \
    *(bf16x8*)(lds + (NBUF)*65536 + aphys0 + g*1024) = w_; \
  } \
}

// A is linear [256 rows][128B] swizzled; row = wr*128 + MH*64 + mf*16 + lr (same eff. rows as R7)
#define READ_A(MH, BUF) \
  _Pragma("unroll") \
  for (int mf = 0; mf < 4; ++mf) { \
    int ar_ = wr*128 + (MH)*64 + mf*16 + lr; \
    _Pragma("unroll") \
    for (int kk = 0; kk < 2; ++kk) \
      a[mf][kk] = *(const bf16x8*)(lds + (BUF)*65536 + ar_*128 + ((kk*64 + hi16) ^ ((ar_&7)<<4))); \
  }
#define READ_B(NH, BUF, BREG) \
  _Pragma("unroll") \
  for (int nf = 0; nf < 2; ++nf) { \
    int br_ = (NH)*128 + wc*32 + nf*16 + lr; \
    _Pragma("unroll") \
    for (int kk = 0; kk < 2; ++kk) \
      BREG[nf][kk] = *(const bf16x8*)(lds + (BUF)*65536 + 32768 + br_*128 + ((kk*64 + hi16) ^ ((br_&7)<<4))); \
  }
#define MFMA_BLOCK(MH, NH, BREG) \
  __builtin_amdgcn_s_setprio(1); \
  _Pragma("unroll") \
  for (int mf = 0; mf < 4; ++mf) \
    _Pragma("unroll") \
    for (int nf = 0; nf < 2; ++nf) \
      _Pragma("unroll") \
      for (int kk = 0; kk < 2; ++kk) \
        acc[(MH)*4+mf][(NH)*2+nf] = __builtin_amdgcn_mfma_f32_16x16x32_bf16( \
            a[mf][kk], BREG[nf][kk], acc[(MH)*4+mf][(NH)*2+nf], 0, 0, 0); \
  __builtin_amdgcn_s_setprio(0);

  f32x4 acc[8][4];
  #pragma unroll
  for (int i = 0; i < 8; ++i)
    #pragma unroll
    for (int n = 0; n < 4; ++n) { acc[i][n].x = 0.f; acc[i][n].y = 0.f; acc[i][n].z = 0.f; acc[i][n].w = 0.f; }

  bf16x8 a[4][2], b0[2][2], b1[2][2];
  f32x4 va[8];

  // Prologue: full tile 0 -> buf0.
  STAGE_B(0, 0, 0);
  STAGE_B(1, 0, 0);
  LOAD_A2(0, 0);
  LOAD_A2(2, 0);
  WRITE_A2(0, 0);
  WRITE_A2(2, 0);
  LGKM0();
  VMCNT(0);
  BAR();

  for (int kt = 0; kt < 32; ++kt) {
    const int buf = kt & 1, nbuf = buf ^ 1;
    const int k1 = (kt + 1) * 64;

    if (kt < 31) {
      STAGE_B(0, nbuf, k1);
      STAGE_B(1, nbuf, k1);
      LOAD_A2(0, k1);
    }
    READ_A(0, buf);
    READ_B(0, buf, b0);
    READ_B(1, buf, b1);
    SBAR0();
    MFMA_BLOCK(0, 0, b0);
    if (kt < 31) LOAD_A2(2, k1);
    MFMA_BLOCK(0, 1, b1);
    READ_A(1, buf);
    MFMA_BLOCK(1, 0, b0);
    if (kt < 31) WRITE_A2(0, nbuf);
    MFMA_BLOCK(1, 1, b1);
    if (kt < 31) WRITE_A2(2, nbuf);
    LGKM0();
    if (kt < 31) { VMCNT(0); }
    BAR();
  }

  // ---- LoRA epilogue (validated): zero-padded 16x16x32 MFMA per frag ----
  const int batch = rowbase >> 11;
  bf16x8 zf = (bf16x8)(short)0;
  bf16x8 ea[8], eb[4];
  #pragma unroll
  for (int i = 0; i < 8; ++i) {
    if (hi < 2)
      ea[i] = *(const bf16x8*)(xa + (size_t)(rowbase + wr * 128 + i * 16 + lr) * 16 + hi * 8);
    else
      ea[i] = zf;
  }
  #pragma unroll
  for (int n = 0; n < 4; ++n) {
    if (hi < 2)
      eb[n] = *(const bf16x8*)(Brt + ((size_t)batch * 2048 + colbase + wc * 64 + n * 16 + lr) * 16 + hi * 8);
    else
      eb[n] = zf;
  }
  #pragma unroll
  for (int i = 0; i < 8; ++i)
    #pragma unroll
    for (int n = 0; n < 4; ++n)
      acc[i][n] = __builtin_amdgcn_mfma_f32_16x16x32_bf16(ea[i], eb[n], acc[i][n], 0, 0, 0);

  // ---- bias + store (C/D: col = lane&15, row = (lane>>4)*4 + j) ----
  #pragma unroll
  for (int n = 0; n < 4; ++n) {
    int col = colbase + wc * 64 + n * 16 + lr;
    float bbv = bias[col];
    #pragma unroll
    for (int i = 0; i < 8; ++i) {
      int r0 = rowbase + wr * 128 + i * 16 + hi * 4;
      #pragma unroll
      for (int j = 0; j < 4; ++j)
        out[(size_t)(r0 + j) * 2048 + col] = acc[i][n][j] + bbv;
    }
  }
#undef GL16
#undef STAGE_B
#undef LOAD_A2
#undef WRITE_A2
#undef READ_A
#undef READ_B
#undef MFMA_BLOCK
}

extern "C" void kernel_launch(void* const* d_in, const int* in_sizes, int n_in,
                              void* d_out, int out_size, void* d_ws, size_t ws_size,
                              hipStream_t stream) {
  const float* x      = (const float*)d_in[0];   // [8][2048][2048]
  const float* W      = (const float*)d_in[1];   // [2048][2048]
  const float* bias   = (const float*)d_in[2];   // [2048]
  const float* logits = (const float*)d_in[3];   // [32][8]
  const float* A      = (const float*)d_in[4];   // [1][8][2048][16]
  const float* B      = (const float*)d_in[5];   // [1][8][16][2048]
  const int*   tasks  = (const int*)d_in[6];     // [8]
  float* out = (float*)d_out;

  char* ws = (char*)d_ws;
  unsigned short* Wb  = (unsigned short*)(ws + 67108864);              //  8388608 B
  unsigned short* xa  = (unsigned short*)(ws + 67108864 + 8388608);    //   524288 B
  unsigned short* Art = (unsigned short*)(ws + 67108864 + 8388608 + 524288);
  unsigned short* Brt = (unsigned short*)(ws + 67108864 + 8388608 + 1048576);

  combine_wconv_kernel<<<192, 256, 0, stream>>>(logits, tasks, A, B, W, Art, Brt, Wb);
  xa_kernel<<<1024, 256, 0, stream>>>(x, Art, xa);
  gemm_kernel<<<512, 512, 0, stream>>>(x, Wb, bias, xa, Brt, out);
}

// Round 13
// 185.744 us; speedup vs baseline: 1.0126x; 1.0126x over previous
//
#include <hip/hip_runtime.h>

typedef __attribute__((ext_vector_type(4))) float f32x4;
typedef __attribute__((ext_vector_type(8))) short bf16x8;

__device__ __forceinline__ unsigned short f2b(float f) {
  unsigned u = __float_as_uint(f);
  u = (u + 0x7FFFu + ((u >> 16) & 1u)) >> 16;
  return (unsigned short)u;
}

#define BAR() asm volatile("s_barrier" ::: "memory")
#define VMCNT(N) asm volatile("s_waitcnt vmcnt(" #N ")" ::: "memory")
#define SBAR0() __builtin_amdgcn_sched_barrier(0)

// ---------------- K1: {selector + skill-mix} ∪ {W f32->bf16} ----------------
// Blocks [0,64): combine (one thread per (b,i)); blocks [64,192): W conversion.
__global__ void combine_wconv_kernel(const float* __restrict__ logits,   // [32][8]
                                     const int*   __restrict__ tasks,    // [8]
                                     const float* __restrict__ A,        // [8][2048][16]
                                     const float* __restrict__ B,        // [8][16][2048]
                                     const float* __restrict__ W,        // [2048][2048]
                                     unsigned short* __restrict__ Art,   // [8][16][2048]
                                     unsigned short* __restrict__ Brt,   // [8][2048][16]
                                     unsigned short* __restrict__ Wb)    // [2048][2048]
{
  int blk = blockIdx.x;
  int tid = threadIdx.x;
  if (blk >= 64) {
    int idx0 = (blk - 64) * 256 + tid;
    #pragma unroll
    for (int c = 0; c < 32; ++c) {
      size_t i = ((size_t)idx0 + (size_t)c * 32768) * 4;
      f32x4 v = *(const f32x4*)(W + i);
      ushort4 o;
      o.x = f2b(v.x); o.y = f2b(v.y); o.z = f2b(v.z); o.w = f2b(v.w);
      *(ushort4*)(Wb + i) = o;
    }
    return;
  }
  int idx = blk * 256 + tid;
  int b = idx >> 11;
  int i = idx & 2047;
  int task = tasks[b];
  float p[8]; float s = 0.f;
  #pragma unroll
  for (int t = 0; t < 8; ++t) {
    float l = logits[task * 8 + t];
    float e = 1.f / (1.f + __expf(-l));
    p[t] = e; s += e;
  }
  float inv = 1.f / (s + 1e-12f);
  #pragma unroll
  for (int t = 0; t < 8; ++t) p[t] *= inv;

  float ar[16];
  #pragma unroll
  for (int r = 0; r < 16; ++r) ar[r] = 0.f;
  for (int t = 0; t < 8; ++t) {
    const float* ap = A + ((size_t)t * 2048 + i) * 16;
    float pt = p[t];
    #pragma unroll
    for (int r = 0; r < 16; ++r) ar[r] += pt * ap[r];
  }
  #pragma unroll
  for (int r = 0; r < 16; ++r)
    Art[((size_t)b * 16 + r) * 2048 + i] = f2b(ar[r]);

  float br[16];
  #pragma unroll
  for (int r = 0; r < 16; ++r) br[r] = 0.f;
  for (int t = 0; t < 8; ++t) {
    float pt = p[t];
    #pragma unroll
    for (int r = 0; r < 16; ++r) br[r] += pt * B[((size_t)t * 16 + r) * 2048 + i];
  }
  #pragma unroll
  for (int r = 0; r < 16; ++r)
    Brt[((size_t)b * 2048 + i) * 16 + r] = f2b(br[r] * 0.0625f);
}

// ---------------- K2: prep = x f32->bf16 + xa = x@A_mix ----------------
// 1024 blocks x 256 thr; 16 rows/block; wave wv owns K-quarter; LDS cross-wave reduce.
__global__ void prep_kernel(const float* __restrict__ x,            // [16384][2048]
                            const unsigned short* __restrict__ Art, // [8][16][2048]
                            unsigned short* __restrict__ xb,        // [16384][2048]
                            unsigned short* __restrict__ xa)        // [16384][16]
{
  __shared__ float red[4][16][16];
  int blk = blockIdx.x;
  int tid = threadIdx.x;
  int lane = tid & 63, wv = tid >> 6;
  int lr = lane & 15, hi = lane >> 4;
  int rowbase = blk * 16;
  int batch = rowbase >> 11;
  int row = rowbase + lr;
  f32x4 acc; acc.x = 0.f; acc.y = 0.f; acc.z = 0.f; acc.w = 0.f;
  const float* xrow = x + (size_t)row * 2048 + wv * 512 + hi * 8;
  unsigned short* xbrow = xb + (size_t)row * 2048 + wv * 512 + hi * 8;
  const unsigned short* artrow = Art + ((size_t)batch * 16 + lr) * 2048 + wv * 512 + hi * 8;
  #pragma unroll
  for (int ks = 0; ks < 16; ++ks) {
    f32x4 v0 = *(const f32x4*)(xrow + ks * 32);
    f32x4 v1 = *(const f32x4*)(xrow + ks * 32 + 4);
    bf16x8 av;
    av[0] = (short)f2b(v0.x); av[1] = (short)f2b(v0.y);
    av[2] = (short)f2b(v0.z); av[3] = (short)f2b(v0.w);
    av[4] = (short)f2b(v1.x); av[5] = (short)f2b(v1.y);
    av[6] = (short)f2b(v1.z); av[7] = (short)f2b(v1.w);
    *(bf16x8*)(xbrow + ks * 32) = av;
    bf16x8 bv = *(const bf16x8*)(artrow + ks * 32);
    acc = __builtin_amdgcn_mfma_f32_16x16x32_bf16(av, bv, acc, 0, 0, 0);
  }
  #pragma unroll
  for (int j = 0; j < 4; ++j) red[wv][hi * 4 + j][lr] = acc[j];
  __syncthreads();
  int rr = tid >> 4, cc = tid & 15;
  float s = red[0][rr][cc] + red[1][rr][cc] + red[2][rr][cc] + red[3][rr][cc];
  xa[(size_t)(rowbase + rr) * 16 + cc] = f2b(s);
}

// ---------------- K3: 256x256 GEMM (R7 schedule: best measured 132.9us / 43% MfmaUtil / 0 conflicts) ----------------
// 512 thr = 8 waves (2 x 4); per-wave out 128x64; LDS 128KB 2-buf; 4 barriers/K-tile;
// reads one phase ahead; sched_barrier(0) pins {reads,stage} before each MFMA burst.
// Structural note (R1-R12 evidence): per-K-tile LDS ingest floor = 256KB (~3010 cyc) vs MFMA
// 2048 cyc -> LDS-bound at perfect overlap; measured 44% MfmaUtil reflects hipcc's overlap
// quality. Six schedule variants bracket 42-44%; deeper interleave or B-removal spills/thrashes.
// vmcnt LEDGER: entry invariant [A0'(kt+1)x2, B0'(kt+1)x2] in flight;
//  ph2-end VMCNT(4) lands A0',B0'(kt+1) (3-phase flight); ph4-end VMCNT(4) lands A1',B1'(kt+1).
// WAR: every staged region overwritten >=3 barriers after its last read. Tail: kt=30 ph4 VMCNT(0).
__global__ __launch_bounds__(512)
void gemm_kernel(const unsigned short* __restrict__ xb,  // [16384][2048] bf16
                 const unsigned short* __restrict__ Wb,  // [2048][2048]  bf16 (row = out col)
                 const float* __restrict__ bias,         // [2048]
                 const unsigned short* __restrict__ xa,  // [16384][16]   bf16
                 const unsigned short* __restrict__ Brt, // [8][2048][16] bf16 (pre-scaled 1/16)
                 float* __restrict__ out)                // [16384][2048] f32
{
  __shared__ __align__(16) char lds[131072];
  const int tid = threadIdx.x;
  const int lane = tid & 63;
  const int wv = tid >> 6;
  const int wr = wv >> 2, wc = wv & 3;
  const int lr = lane & 15, hi = lane >> 4;
  const int hi16 = hi * 16;

  const int bid = blockIdx.x;
  const int swz = (bid & 7) * 64 + (bid >> 3);
  const int tm = swz >> 3, tn = swz & 7;
  const int rowbase = tm * 256, colbase = tn * 256;

  const int row0 = tid >> 3;
  const int cb0 = (tid & 7) * 16;
  const int scb_e = (cb0 ^ ((row0 & 7) << 4)) >> 1;
  const int rb5 = ((row0 >> 5) << 6) + (row0 & 31);

#define GL16(LDSOFF, GPTR) \
  __builtin_amdgcn_global_load_lds((const __attribute__((address_space(1))) unsigned int*)(GPTR), \
      (__attribute__((address_space(3))) unsigned int*)(lds + (LDSOFF)), 16, 0, 0)

#define STAGE_A(MH, DBUF, KOFF) { \
  const unsigned short* g_ = xb + (size_t)(rowbase + (MH)*64 + row0) * 2048 + (KOFF) + scb_e; \
  GL16((DBUF)*65536 + (MH)*16384 + tid*16, g_); \
  GL16((DBUF)*65536 + (MH)*16384 + 8192 + tid*16, g_ + 128*2048); \
}
#define STAGE_B(NH, DBUF, KOFF) { \
  const unsigned short* g_ = Wb + (size_t)(colbase + (NH)*32 + rb5) * 2048 + (KOFF) + scb_e; \
  GL16((DBUF)*65536 + 32768 + (NH)*16384 + tid*16, g_); \
  GL16((DBUF)*65536 + 32768 + (NH)*16384 + 8192 + tid*16, g_ + 128*2048); \
}

#define READ_A(MH, ABASE) \
  _Pragma("unroll") \
  for (int mf = 0; mf < 4; ++mf) { \
    int ar_ = (MH)*128 + wr*64 + mf*16 + lr; \
    _Pragma("unroll") \
    for (int kk = 0; kk < 2; ++kk) \
      a[mf][kk] = *(const bf16x8*)((ABASE) + ar_*128 + ((kk*64 + hi16) ^ ((ar_&7)<<4))); \
  }
#define READ_B(NH, BBASE, BREG) \
  _Pragma("unroll") \
  for (int nf = 0; nf < 2; ++nf) { \
    int br_ = (NH)*128 + wc*32 + nf*16 + lr; \
    _Pragma("unroll") \
    for (int kk = 0; kk < 2; ++kk) \
      BREG[nf][kk] = *(const bf16x8*)((BBASE) + br_*128 + ((kk*64 + hi16) ^ ((br_&7)<<4))); \
  }
#define MFMA_BLOCK(MH, NH, BREG) \
  __builtin_amdgcn_s_setprio(1); \
  _Pragma("unroll") \
  for (int mf = 0; mf < 4; ++mf) \
    _Pragma("unroll") \
    for (int nf = 0; nf < 2; ++nf) \
      _Pragma("unroll") \
      for (int kk = 0; kk < 2; ++kk) \
        acc[(MH)*4+mf][(NH)*2+nf] = __builtin_amdgcn_mfma_f32_16x16x32_bf16( \
            a[mf][kk], BREG[nf][kk], acc[(MH)*4+mf][(NH)*2+nf], 0, 0, 0); \
  __builtin_amdgcn_s_setprio(0);

  f32x4 acc[8][4];
  #pragma unroll
  for (int i = 0; i < 8; ++i)
    #pragma unroll
    for (int n = 0; n < 4; ++n) { acc[i][n].x = 0.f; acc[i][n].y = 0.f; acc[i][n].z = 0.f; acc[i][n].w = 0.f; }

  bf16x8 a[4][2], b0[2][2], b1[2][2];

  // Prologue: tile0 (8 loads) + A0(1),B0(1) (4 loads). VMCNT(4) lands tile0.
  STAGE_A(0, 0, 0);
  STAGE_B(0, 0, 0);
  STAGE_A(1, 0, 0);
  STAGE_B(1, 0, 0);
  STAGE_A(0, 1, 64);
  STAGE_B(0, 1, 64);
  VMCNT(4);
  BAR();
  READ_A(0, lds);                 // a  <- A0(0)
  READ_B(0, lds + 32768, b0);     // b0 <- B0(0)

  for (int kt = 0; kt < 32; ++kt) {
    const int buf = kt & 1, nbuf = buf ^ 1;
    const char* Ab  = lds + buf * 65536;
    const char* Bb  = Ab + 32768;
    const char* Abn = lds + nbuf * 65536;
    const char* Bbn = Abn + 32768;
    const int k1 = (kt + 1) * 64, k2 = (kt + 2) * 64;

    // ph1: {rd b1, stage A1'} FENCE {MM Q00}
    BAR();
    READ_B(1, Bb, b1);                    // b1 <- B1(kt)
    if (kt < 31) STAGE_A(1, nbuf, k1);
    SBAR0();
    MFMA_BLOCK(0, 0, b0);                 // Q00

    // ph2: {stage B1'} FENCE {MM Q01}; then rd a<-A1(kt) (reg-WAR pins it after MM)
    BAR();
    if (kt < 31) STAGE_B(1, nbuf, k1);
    SBAR0();
    MFMA_BLOCK(0, 1, b1);                 // Q01
    READ_A(1, Ab);
    if (kt < 31) { VMCNT(4); }

    // ph3: {stage A0'} FENCE {MM Q10}; then rd b0<-B0(kt+1)
    BAR();
    if (kt < 30) STAGE_A(0, buf, k2);
    SBAR0();
    MFMA_BLOCK(1, 0, b0);                 // Q10
    if (kt < 31) READ_B(0, Bbn, b0);

    // ph4: {stage B0'} FENCE {MM Q11}; then rd a<-A0(kt+1)
    BAR();
    if (kt < 30) STAGE_B(0, buf, k2);
    SBAR0();
    MFMA_BLOCK(1, 1, b1);                 // Q11
    if (kt < 31) READ_A(0, Abn);
    if (kt < 30) { VMCNT(4); }
    else if (kt == 30) { VMCNT(0); }
  }

  // ---- LoRA epilogue: zero-padded 16x16x32 MFMA per frag ----
  const int batch = rowbase >> 11;
  bf16x8 zf = (bf16x8)(short)0;
  bf16x8 ea[8], eb[4];
  #pragma unroll
  for (int i = 0; i < 8; ++i) {
    if (hi < 2)
      ea[i] = *(const bf16x8*)(xa + (size_t)(rowbase + wr * 128 + i * 16 + lr) * 16 + hi * 8);
    else
      ea[i] = zf;
  }
  #pragma unroll
  for (int n = 0; n < 4; ++n) {
    if (hi < 2)
      eb[n] = *(const bf16x8*)(Brt + ((size_t)batch * 2048 + colbase + wc * 64 + n * 16 + lr) * 16 + hi * 8);
    else
      eb[n] = zf;
  }
  #pragma unroll
  for (int i = 0; i < 8; ++i)
    #pragma unroll
    for (int n = 0; n < 4; ++n)
      acc[i][n] = __builtin_amdgcn_mfma_f32_16x16x32_bf16(ea[i], eb[n], acc[i][n], 0, 0, 0);

  // ---- bias + store (C/D: col = lane&15, row = (lane>>4)*4 + j) ----
  #pragma unroll
  for (int n = 0; n < 4; ++n) {
    int col = colbase + wc * 64 + n * 16 + lr;
    float bbv = bias[col];
    #pragma unroll
    for (int i = 0; i < 8; ++i) {
      int r0 = rowbase + wr * 128 + i * 16 + hi * 4;
      #pragma unroll
      for (int j = 0; j < 4; ++j)
        out[(size_t)(r0 + j) * 2048 + col] = acc[i][n][j] + bbv;
    }
  }
#undef GL16
#undef STAGE_A
#undef STAGE_B
#undef READ_A
#undef READ_B
#undef MFMA_BLOCK
}

extern "C" void kernel_launch(void* const* d_in, const int* in_sizes, int n_in,
                              void* d_out, int out_size, void* d_ws, size_t ws_size,
                              hipStream_t stream) {
  const float* x      = (const float*)d_in[0];   // [8][2048][2048]
  const float* W      = (const float*)d_in[1];   // [2048][2048]
  const float* bias   = (const float*)d_in[2];   // [2048]
  const float* logits = (const float*)d_in[3];   // [32][8]
  const float* A      = (const float*)d_in[4];   // [1][8][2048][16]
  const float* B      = (const float*)d_in[5];   // [1][8][16][2048]
  const int*   tasks  = (const int*)d_in[6];     // [8]
  float* out = (float*)d_out;

  char* ws = (char*)d_ws;
  unsigned short* xb  = (unsigned short*)(ws);                         // 67108864 B
  unsigned short* Wb  = (unsigned short*)(ws + 67108864);              //  8388608 B
  unsigned short* xa  = (unsigned short*)(ws + 67108864 + 8388608);    //   524288 B
  unsigned short* Art = (unsigned short*)(ws + 67108864 + 8388608 + 524288);
  unsigned short* Brt = (unsigned short*)(ws + 67108864 + 8388608 + 1048576);

  combine_wconv_kernel<<<192, 256, 0, stream>>>(logits, tasks, A, B, W, Art, Brt, Wb);
  prep_kernel<<<1024, 256, 0, stream>>>(x, Art, xb, xa);
  gemm_kernel<<<512, 512, 0, stream>>>(xb, Wb, bias, xa, Brt, out);
}